// Round 9
// baseline (500.953 us; speedup 1.0000x reference)
//
#include <hip/hip_runtime.h>
#include <hip/hip_bf16.h>
#include <math.h>

#define NN   100000
#define EE   1600000
#define ETOT 1700000   // EE + NN self loops
#define MM   40
#define HID  128
#define LAT  64
#define NB   391       // ceil(NN/256) buckets of 256 nodes
#define CHUNK 4096     // edges per bin_pass block

typedef unsigned short u16;
typedef unsigned int   u32;
typedef unsigned long long u64;

typedef __attribute__((ext_vector_type(8))) short bf16x8;
typedef __attribute__((ext_vector_type(4))) float f32x4;
typedef __attribute__((ext_vector_type(2))) float f32x2;

__device__ __forceinline__ float bf2f(u16 a) {
    return __uint_as_float(((u32)a) << 16);
}
__device__ __forceinline__ u16 f2bf(float f) {
    u32 u = __float_as_uint(f);
    u32 r = (u + 0x7fffu + ((u >> 16) & 1u)) >> 16;
    return (u16)r;
}
__device__ __forceinline__ f32x2 unpk(u32 u) {
    f32x2 r;
    r.x = __uint_as_float(u << 16);
    r.y = __uint_as_float(u & 0xffff0000u);
    return r;
}
// tanh-form GELU via sigmoid: x * sigmoid(1.595769x + 0.0713548x^3); |err vs exact| <= ~3e-4
__device__ __forceinline__ float gelu_t(float x) {
    float x2 = x * x;
    float y = x * fmaf(0.0713548162726f, x2, 1.59576912161f);
    return x / (1.f + __expf(-y));
}

// f32 vector pack offsets (floats)
#define Vbp   0
#define Vatt1 128
#define Vb1   256
#define Vg1   384
#define Vbe1  512
#define Vatt2 640
#define Vb2   768
#define Vg2   896
#define Vbe2  1024
#define Vbo   1152
#define VTOT  1216

// bf16 transposed weight pack offsets (u16 elements)
#define BWp   0        // [128][64]  (K=40 zero-padded to 64)
#define BW1l  8192     // [128][128]
#define BW1r  24576    // adjacent to BW1l (gridDim.y=2 panel trick)
#define BW2l  40960
#define BW2r  57344
#define BWo   73728    // [64][128], padded to 128 rows (zeros)
#define BTOT  90112

// ---------------- dtype sniff ----------------
__global__ void sniff_kernel(const u32* __restrict__ ei_raw, const u32* __restrict__ x_raw,
                             int* __restrict__ flags) {
    if (threadIdx.x != 0 || blockIdx.x != 0) return;
    int allz = 1;
    for (int i = 1; i < 256; i += 2) allz &= (ei_raw[i] == 0u);
    flags[0] = allz;
    int bf_like = 0;
    for (int i = 0; i < 64; i++) {
        u16 lo = (u16)(x_raw[i] & 0xffffu);
        int e = (lo >> 7) & 0xFF;
        if (e >= 118 && e <= 133) bf_like++;
    }
    flags[1] = (bf_like >= 48) ? 1 : 0;
}

__device__ __forceinline__ void edge_decode(const int* __restrict__ ei, int is64, int e,
                                            int& src, int& dst) {
    if (e < EE) {
        src = is64 ? ei[2 * e] : ei[e];
        int idx = EE + e;
        dst = is64 ? ei[2 * idx] : ei[idx];
    } else {
        src = e - EE; dst = src;
    }
}

// ---------------- normalize x -> bf16 ----------------
__global__ void normx_kernel(const void* __restrict__ in, u16* __restrict__ out, int n,
                             const int* __restrict__ flags) {
    int i = blockIdx.x * 256 + threadIdx.x;
    if (i >= n) return;
    out[i] = flags[1] ? ((const u16*)in)[i] : f2bf(((const float*)in)[i]);
}

// ---------------- pack small vectors to f32 ----------------
__global__ void norm_vec_kernel(
    const void* p0, const void* p1, const void* p2, const void* p3, const void* p4,
    const void* p5, const void* p6, const void* p7, const void* p8, const void* p9,
    float* __restrict__ out, const int* __restrict__ flags)
{
    int i = blockIdx.x * 256 + threadIdx.x;
    if (i >= VTOT) return;
    const int offs[11] = {Vbp, Vatt1, Vb1, Vg1, Vbe1, Vatt2, Vb2, Vg2, Vbe2, Vbo, VTOT};
    const void* ps[10] = {p0,p1,p2,p3,p4,p5,p6,p7,p8,p9};
    int s = 0;
#pragma unroll
    for (int k = 1; k < 10; k++) s += (i >= offs[k]) ? 1 : 0;
    int j = i - offs[s];
    const void* p = ps[s];
    out[i] = flags[1] ? bf2f(((const u16*)p)[j]) : ((const float*)p)[j];
}

// ---------------- transpose weights to bf16 Wt[n][k] ----------------
__global__ void norm_wt_kernel(
    const void* w0, const void* w1, const void* w2, const void* w3, const void* w4,
    const void* w5, u16* __restrict__ out, const int* __restrict__ flags)
{
    int i = blockIdx.x * 256 + threadIdx.x;
    if (i >= BTOT) return;
    const int offs[7] = {BWp, BW1l, BW1r, BW2l, BW2r, BWo, BTOT};
    const int Ks[6]   = {40, 128, 128, 128, 128, 128};
    const int Ncs[6]  = {128, 128, 128, 128, 128, 64};
    const int Kps[6]  = {64, 128, 128, 128, 128, 128};
    const void* ps[6] = {w0,w1,w2,w3,w4,w5};
    int s = 0;
#pragma unroll
    for (int k = 1; k < 6; k++) s += (i >= offs[k]) ? 1 : 0;
    int j = i - offs[s];
    int Kp = Kps[s];
    int n = j / Kp, k = j % Kp;
    u16 v = 0;
    if (k < Ks[s] && n < Ncs[s]) {
        const void* p = ps[s];
        int src = k * Ncs[s] + n;
        v = flags[1] ? ((const u16*)p)[src] : f2bf(((const float*)p)[src]);
    }
    out[i] = v;
}

// ---------------- CSR build: 2-pass LDS-binned counting sort ----------------
__global__ __launch_bounds__(256) void bucket_hist_kernel(
    const int* __restrict__ ei, const int* __restrict__ flags, u32* __restrict__ gbucket)
{
    __shared__ u32 h[512];
    int t = threadIdx.x;
    h[t] = 0; h[t + 256] = 0;
    __syncthreads();
    int is64 = flags[0];
    int base = blockIdx.x * CHUNK;
#pragma unroll
    for (int j = 0; j < CHUNK / 256; j++) {
        int e = base + j * 256 + t;
        if (e < ETOT) {
            int src, dst;
            edge_decode(ei, is64, e, src, dst);
            atomicAdd(&h[dst >> 8], 1u);
        }
    }
    __syncthreads();
    if (h[t])       atomicAdd(&gbucket[t], h[t]);
    if (h[t + 256]) atomicAdd(&gbucket[t + 256], h[t + 256]);
}

__global__ __launch_bounds__(256) void bucket_scan_kernel(
    const u32* __restrict__ gbucket, u32* __restrict__ bbase, u32* __restrict__ bcursor)
{
    __shared__ u32 ts[256];
    int t = threadIdx.x;
    u32 s0 = (2 * t     < NB) ? gbucket[2 * t]     : 0;
    u32 s1 = (2 * t + 1 < NB) ? gbucket[2 * t + 1] : 0;
    u32 tsum = s0 + s1;
    ts[t] = tsum; __syncthreads();
    for (int d = 1; d < 256; d <<= 1) {
        u32 v = (t >= d) ? ts[t - d] : 0;
        __syncthreads();
        ts[t] += v;
        __syncthreads();
    }
    u32 excl = ts[t] - tsum;
    bbase[2 * t] = excl;          bcursor[2 * t] = excl;
    bbase[2 * t + 1] = excl + s0; bcursor[2 * t + 1] = excl + s0;
    if (2 * t == NB - 1 || 2 * t + 1 == NB - 1) bbase[NB] = ETOT;
}

__global__ __launch_bounds__(256) void bin_pass_kernel(
    const int* __restrict__ ei, const int* __restrict__ flags,
    u32* __restrict__ bcursor, u64* __restrict__ pairs)
{
    __shared__ u32 bh[512];
    __shared__ u32 boff[512];
    __shared__ u32 bbs[512];
    __shared__ u32 bcur[512];
    __shared__ u64 stage[CHUNK];
    __shared__ u32 ts[256];

    int t = threadIdx.x;
    bh[t] = 0; bh[t + 256] = 0;
    __syncthreads();
    int is64 = flags[0];
    int base = blockIdx.x * CHUNK;
    int chunk_n = ETOT - base; if (chunk_n > CHUNK) chunk_n = CHUNK;

#pragma unroll
    for (int j = 0; j < CHUNK / 256; j++) {
        int e = base + j * 256 + t;
        if (e < ETOT) {
            int src, dst;
            edge_decode(ei, is64, e, src, dst);
            atomicAdd(&bh[dst >> 8], 1u);
        }
    }
    __syncthreads();
    u32 s0 = bh[2 * t], s1 = bh[2 * t + 1];
    u32 tsum = s0 + s1;
    ts[t] = tsum; __syncthreads();
    for (int d = 1; d < 256; d <<= 1) {
        u32 v = (t >= d) ? ts[t - d] : 0;
        __syncthreads();
        ts[t] += v;
        __syncthreads();
    }
    u32 excl = ts[t] - tsum;
    boff[2 * t] = excl; boff[2 * t + 1] = excl + s0;
    bcur[2 * t] = excl; bcur[2 * t + 1] = excl + s0;
    __syncthreads();
    if (t < NB && bh[t]) bbs[t] = atomicAdd(&bcursor[t], bh[t]);
    if (t + 256 < NB && bh[t + 256]) bbs[t + 256] = atomicAdd(&bcursor[t + 256], bh[t + 256]);
    __syncthreads();
#pragma unroll
    for (int j = 0; j < CHUNK / 256; j++) {
        int e = base + j * 256 + t;
        if (e < ETOT) {
            int src, dst;
            edge_decode(ei, is64, e, src, dst);
            u32 pos = atomicAdd(&bcur[dst >> 8], 1u);
            stage[pos] = (u64)src | ((u64)dst << 32);
        }
    }
    __syncthreads();
    for (int i = t; i < chunk_n; i += 256) {
        u64 pr = stage[i];
        u32 b = (u32)(pr >> 32) >> 8;
        pairs[(size_t)bbs[b] + (i - boff[b])] = pr;
    }
}

__global__ __launch_bounds__(256) void sort_pass_kernel(
    const u64* __restrict__ pairs, const u32* __restrict__ bbase,
    int* __restrict__ srcs, int* __restrict__ offs)
{
    __shared__ u32 nh[256];
    __shared__ u32 ns[256];
    __shared__ u32 ncur[256];
    int t = threadIdx.x;
    int b = blockIdx.x;
    u32 beg = bbase[b], endp = bbase[b + 1];
    nh[t] = 0;
    __syncthreads();
    for (u32 i = beg + t; i < endp; i += 256) {
        u32 dst = (u32)(pairs[i] >> 32);
        atomicAdd(&nh[dst & 255], 1u);
    }
    __syncthreads();
    u32 cnt = nh[t];
    ns[t] = cnt; __syncthreads();
    for (int d = 1; d < 256; d <<= 1) {
        u32 v = (t >= d) ? ns[t - d] : 0;
        __syncthreads();
        ns[t] += v;
        __syncthreads();
    }
    u32 excl = ns[t] - cnt;
    int id = b * 256 + t;
    if (id <= NN) offs[id] = (int)(beg + excl);
    ncur[t] = excl;
    __syncthreads();
    for (u32 i = beg + t; i < endp; i += 256) {
        u64 pr = pairs[i];
        u32 loc = ((u32)(pr >> 32)) & 255;
        u32 p = atomicAdd(&ncur[loc], 1u);
        srcs[beg + p] = (int)(u32)pr;
    }
}

// ---------------- degree-sorted node permutation (LPT wave scheduling) ----------------
__global__ __launch_bounds__(256) void deg_hist_kernel(
    const int* __restrict__ offs, u32* __restrict__ gdeg)
{
    __shared__ u32 h[256];
    int t = threadIdx.x;
    h[t] = 0;
    __syncthreads();
    int id = blockIdx.x * 256 + t;
    if (id < NN) {
        int d = offs[id + 1] - offs[id];
        d = d < 255 ? d : 255;
        atomicAdd(&h[d], 1u);
    }
    __syncthreads();
    if (h[t]) atomicAdd(&gdeg[t], h[t]);
}

// descending-degree exclusive bases
__global__ __launch_bounds__(256) void deg_scan_kernel(
    const u32* __restrict__ gdeg, u32* __restrict__ dcursor)
{
    __shared__ u32 ts[256];
    int t = threadIdx.x;
    u32 c = gdeg[255 - t];
    ts[t] = c; __syncthreads();
    for (int d = 1; d < 256; d <<= 1) {
        u32 v = (t >= d) ? ts[t - d] : 0;
        __syncthreads();
        ts[t] += v;
        __syncthreads();
    }
    dcursor[255 - t] = ts[t] - c;
}

__global__ __launch_bounds__(256) void deg_scatter_kernel(
    const int* __restrict__ offs, u32* __restrict__ dcursor, int* __restrict__ perm)
{
    __shared__ u32 h[256];
    __shared__ u32 bbs[256];
    __shared__ u32 loc[256];
    int t = threadIdx.x;
    h[t] = 0; loc[t] = 0;
    __syncthreads();
    int id = blockIdx.x * 256 + t;
    int d = 0;
    if (id < NN) {
        d = offs[id + 1] - offs[id];
        d = d < 255 ? d : 255;
        atomicAdd(&h[d], 1u);
    }
    __syncthreads();
    if (h[t]) bbs[t] = atomicAdd(&dcursor[t], h[t]);
    __syncthreads();
    if (id < NN) {
        u32 p = atomicAdd(&loc[d], 1u);
        perm[bbs[d] + p] = id;
    }
}

// ---------------- MFMA GEMM ----------------
__global__ __launch_bounds__(256) void mfma_gemm(
    const u16* __restrict__ A, int lda,
    const u16* __restrict__ Bt, int ldb,
    const float* __restrict__ bias,
    int nrows, int ksteps, int ncols,
    float* __restrict__ outF, u16* __restrict__ outB, u16* __restrict__ outB2, int ldo,
    int mode, const int* __restrict__ flags)
{
    int lane = threadIdx.x & 63;
    int wv = threadIdx.x >> 6;
    int wx = wv & 1, wy = wv >> 1;
    int l16 = lane & 15, quad = lane >> 4;
    int r0 = blockIdx.x * 128 + wx * 64;
    int n0 = wy * 64;

    Bt += (size_t)blockIdx.y * 128 * ldb;
    if (blockIdx.y) outB = outB2;

    f32x4 acc[4][4];
#pragma unroll
    for (int m = 0; m < 4; m++)
#pragma unroll
        for (int n = 0; n < 4; n++) acc[m][n] = (f32x4){0.f, 0.f, 0.f, 0.f};

    const u16* Ap = A + (size_t)(r0 + l16) * lda + quad * 8;
    const u16* Bp = Bt + (size_t)(n0 + l16) * ldb + quad * 8;

    for (int k = 0; k < ksteps; ++k) {
        bf16x8 af[4], bfr[4];
#pragma unroll
        for (int m = 0; m < 4; m++)
            af[m] = *(const bf16x8*)(Ap + (size_t)m * 16 * lda + k * 32);
#pragma unroll
        for (int n = 0; n < 4; n++)
            bfr[n] = *(const bf16x8*)(Bp + (size_t)n * 16 * ldb + k * 32);
#pragma unroll
        for (int m = 0; m < 4; m++)
#pragma unroll
            for (int n = 0; n < 4; n++)
                acc[m][n] = __builtin_amdgcn_mfma_f32_16x16x32_bf16(af[m], bfr[n], acc[m][n], 0, 0, 0);
    }

    int mk = mode;
    if (mk < 0) mk = flags[1] ? 2 : 1;

#pragma unroll
    for (int m = 0; m < 4; m++) {
#pragma unroll
        for (int n = 0; n < 4; n++) {
            int col = n0 + n * 16 + l16;
            float bb = (bias != nullptr && col < ncols) ? bias[col] : 0.f;
#pragma unroll
            for (int reg = 0; reg < 4; reg++) {
                int row = r0 + m * 16 + quad * 4 + reg;
                if (row < nrows && col < ncols) {
                    float v = acc[m][n][reg] + bb;
                    if (mk & 1) outF[(size_t)row * ldo + col] = v;
                    if (mk & 2) outB[(size_t)row * ldo + col] = f2bf(v);
                }
            }
        }
    }
}

// ---------------- fused GATv2 agg + bias + GELU + residual + LayerNorm ----------------
// 4 dst per wave via degree-sorted perm (deg-aligned waves, LPT order).
// 3 edges per dst in flight per iteration.
__global__ __launch_bounds__(256) void gat_agg_kernel(
    const u16* __restrict__ hl, const u16* __restrict__ hr, const u16* __restrict__ hresb,
    const float* __restrict__ att, const float* __restrict__ bias,
    const float* __restrict__ gamma, const float* __restrict__ beta,
    const int* __restrict__ offs, const int* __restrict__ srcs,
    const int* __restrict__ perm,
    u16* __restrict__ outb)
{
    int lane = threadIdx.x & 63;
    int sub = lane >> 4;
    int r = lane & 15;
    int c0 = r * 8;
    int gi = (blockIdx.x * 4 + (threadIdx.x >> 6)) * 4 + sub;    // grid = NN/16 blocks
    int dst = perm[gi];

    int start = offs[dst];
    int deg = offs[dst + 1] - start;    // >= 1 (self loop)
    int dm = deg - 1;

    f32x2 hr2[4], av2[4];
    {
        uint4 q = *(const uint4*)(hr + ((size_t)dst << 7) + c0);
        hr2[0] = unpk(q.x); hr2[1] = unpk(q.y); hr2[2] = unpk(q.z); hr2[3] = unpk(q.w);
        float4 a0 = *(const float4*)&att[c0];
        float4 a1 = *(const float4*)&att[c0 + 4];
        av2[0] = (f32x2){a0.x, a0.y}; av2[1] = (f32x2){a0.z, a0.w};
        av2[2] = (f32x2){a1.x, a1.y}; av2[3] = (f32x2){a1.z, a1.w};
    }

    // wave-uniform iteration bound = max deg over the 4 sub-groups (≈ equal after sort)
    int md = deg;
    md = max(md, __shfl_xor(md, 16));
    md = max(md, __shfl_xor(md, 32));

    f32x2 acc2[4];
#pragma unroll
    for (int i = 0; i < 4; i++) acc2[i] = (f32x2){0.f, 0.f};
    float s = 0.f;

    // prefetch: rows for edges 0..2, srcs for edges 3..5
    int sa = srcs[start];
    int sb = srcs[start + (1 < dm ? 1 : dm)];
    int sc = srcs[start + (2 < dm ? 2 : dm)];
    uint4 qa = *(const uint4*)(hl + ((size_t)sa << 7) + c0);
    uint4 qb = *(const uint4*)(hl + ((size_t)sb << 7) + c0);
    uint4 qc = *(const uint4*)(hl + ((size_t)sc << 7) + c0);
    int na = srcs[start + (3 < dm ? 3 : dm)];
    int nb = srcs[start + (4 < dm ? 4 : dm)];
    int nc = srcs[start + (5 < dm ? 5 : dm)];

    int mi = (md + 2) / 3;
    for (int j = 0; j < mi; ++j) {
        int e6 = 3 * j + 6, e7 = 3 * j + 7, e8 = 3 * j + 8;
        int na2 = srcs[start + (e6 < dm ? e6 : dm)];
        int nb2 = srcs[start + (e7 < dm ? e7 : dm)];
        int nc2 = srcs[start + (e8 < dm ? e8 : dm)];
        uint4 qna = *(const uint4*)(hl + ((size_t)na << 7) + c0);
        uint4 qnb = *(const uint4*)(hl + ((size_t)nb << 7) + c0);
        uint4 qnc = *(const uint4*)(hl + ((size_t)nc << 7) + c0);

        f32x2 ha[4], hb[4], hc[4];
        ha[0] = unpk(qa.x); ha[1] = unpk(qa.y); ha[2] = unpk(qa.z); ha[3] = unpk(qa.w);
        hb[0] = unpk(qb.x); hb[1] = unpk(qb.y); hb[2] = unpk(qb.z); hb[3] = unpk(qb.w);
        hc[0] = unpk(qc.x); hc[1] = unpk(qc.y); hc[2] = unpk(qc.z); hc[3] = unpk(qc.w);
        f32x2 pa2 = (f32x2){0.f, 0.f};
        f32x2 pb2 = (f32x2){0.f, 0.f};
        f32x2 pc2 = (f32x2){0.f, 0.f};
#pragma unroll
        for (int i = 0; i < 4; i++) {
            f32x2 za = ha[i] + hr2[i];
            f32x2 zb = hb[i] + hr2[i];
            f32x2 zc = hc[i] + hr2[i];
            f32x2 la = __builtin_elementwise_max(za, za * 0.2f);
            f32x2 lb = __builtin_elementwise_max(zb, zb * 0.2f);
            f32x2 lc = __builtin_elementwise_max(zc, zc * 0.2f);
            pa2 = __builtin_elementwise_fma(av2[i], la, pa2);
            pb2 = __builtin_elementwise_fma(av2[i], lb, pb2);
            pc2 = __builtin_elementwise_fma(av2[i], lc, pc2);
        }
        float pa = pa2.x + pa2.y;
        float pb = pb2.x + pb2.y;
        float pc = pc2.x + pc2.y;
        pa += __shfl_xor(pa, 1); pb += __shfl_xor(pb, 1); pc += __shfl_xor(pc, 1);
        pa += __shfl_xor(pa, 2); pb += __shfl_xor(pb, 2); pc += __shfl_xor(pc, 2);
        int e0 = 3 * j, e1 = 3 * j + 1, e2 = 3 * j + 2;
        float wa = (e0 < deg) ? __expf(pa) : 0.f;
        float wb = (e1 < deg) ? __expf(pb) : 0.f;
        float wc = (e2 < deg) ? __expf(pc) : 0.f;
        s += wa + wb + wc;
        f32x2 wa2 = (f32x2){wa, wa};
        f32x2 wb2 = (f32x2){wb, wb};
        f32x2 wc2 = (f32x2){wc, wc};
#pragma unroll
        for (int i = 0; i < 4; i++)
            acc2[i] = __builtin_elementwise_fma(wa2, ha[i],
                      __builtin_elementwise_fma(wb2, hb[i],
                      __builtin_elementwise_fma(wc2, hc[i], acc2[i])));

        qa = qna; qb = qnb; qc = qnc;
        na = na2; nb = nb2; nc = nc2;
    }

    float inv = 1.f / s;
    float v[8];
    {
        float4 b0 = *(const float4*)&bias[c0];
        float4 b1 = *(const float4*)&bias[c0 + 4];
        float bb[8] = {b0.x,b0.y,b0.z,b0.w,b1.x,b1.y,b1.z,b1.w};
        uint4 qr = *(const uint4*)(hresb + ((size_t)dst << 7) + c0);
        f32x2 rr2[4] = {unpk(qr.x), unpk(qr.y), unpk(qr.z), unpk(qr.w)};
#pragma unroll
        for (int i = 0; i < 4; i++) {
            float t0 = fmaf(acc2[i].x, inv, bb[2*i]);
            float t1 = fmaf(acc2[i].y, inv, bb[2*i+1]);
            v[2*i]   = gelu_t(t0) + rr2[i].x;
            v[2*i+1] = gelu_t(t1) + rr2[i].y;
        }
    }

    // LayerNorm over 128 ch = 16 lanes of this sub-group (offsets 1..8 stay in-group)
    float s1 = 0.f, s2 = 0.f;
#pragma unroll
    for (int k = 0; k < 8; k++) { s1 += v[k]; s2 = fmaf(v[k], v[k], s2); }
#pragma unroll
    for (int off = 1; off < 16; off <<= 1) {
        s1 += __shfl_xor(s1, off);
        s2 += __shfl_xor(s2, off);
    }
    float mu  = s1 * (1.f / 128.f);
    float var = s2 * (1.f / 128.f) - mu * mu;
    float rstd = rsqrtf(var + 1e-5f);

    float4 g0 = *(const float4*)&gamma[c0];
    float4 g1 = *(const float4*)&gamma[c0 + 4];
    float4 be0 = *(const float4*)&beta[c0];
    float4 be1 = *(const float4*)&beta[c0 + 4];
    float gg[8] = {g0.x,g0.y,g0.z,g0.w,g1.x,g1.y,g1.z,g1.w};
    float eb[8] = {be0.x,be0.y,be0.z,be0.w,be1.x,be1.y,be1.z,be1.w};
    float o[8];
#pragma unroll
    for (int k = 0; k < 8; k++) o[k] = fmaf((v[k] - mu) * rstd, gg[k], eb[k]);
    uint4 pk;
    pk.x = (u32)f2bf(o[0]) | ((u32)f2bf(o[1]) << 16);
    pk.y = (u32)f2bf(o[2]) | ((u32)f2bf(o[3]) << 16);
    pk.z = (u32)f2bf(o[4]) | ((u32)f2bf(o[5]) << 16);
    pk.w = (u32)f2bf(o[6]) | ((u32)f2bf(o[7]) << 16);
    *(uint4*)(outb + ((size_t)dst << 7) + c0) = pk;
}

// ---------------- launch ----------------
extern "C" void kernel_launch(void* const* d_in, const int* in_sizes, int n_in,
                              void* d_out, int out_size, void* d_ws, size_t ws_size,
                              hipStream_t stream) {
    const void* x  = d_in[0];
    const int*  ei = (const int*)d_in[1];

    char* ws = (char*)d_ws;
    size_t off = 0;
    auto alloc = [&](size_t bytes) -> void* {
        void* p = ws + off;
        off = (off + bytes + 511) & ~(size_t)511;
        return p;
    };
    u16*   xb      = (u16*)  alloc(((size_t)NN * MM + 8192) * 2);
    float* wv      = (float*)alloc((size_t)VTOT * 4);
    u16*   wbf     = (u16*)  alloc((size_t)BTOT * 2);
    u16*   h0b     = (u16*)  alloc((size_t)(NN + 64) * HID * 2);
    u16*   h1b     = (u16*)  alloc((size_t)(NN + 64) * HID * 2);
    u16*   hlb     = (u16*)  alloc((size_t)NN * HID * 2);
    u16*   hrb     = (u16*)  alloc((size_t)NN * HID * 2);
    int*   offs    = (int*)  alloc((size_t)(NN + 1) * 4);
    u32*   gcnt    = (u32*)  alloc(1024 * 4);   // [0:512) gbucket, [512:768) gdeg, [768:1024) dcursor
    u32*   bbase   = (u32*)  alloc(520 * 4);
    u32*   bcursor = (u32*)  alloc(520 * 4);
    int*   flags   = (int*)  alloc(512);
    int*   perm    = (int*)  alloc((size_t)NN * 4);
    int*   srcs    = (int*)  alloc(((size_t)ETOT + 64) * 4);
    u64*   pairs   = (u64*)  alloc((size_t)ETOT * 8);

    u32* gbucket = gcnt;
    u32* gdeg    = gcnt + 512;
    u32* dcursor = gcnt + 768;

    hipMemsetAsync(gcnt, 0, 768 * 4, stream);   // gbucket + gdeg

    sniff_kernel<<<1, 64, 0, stream>>>((const u32*)ei, (const u32*)x, flags);

    normx_kernel<<<(NN * MM + 255) / 256, 256, 0, stream>>>(x, xb, NN * MM, flags);
    norm_vec_kernel<<<(VTOT + 255) / 256, 256, 0, stream>>>(
        d_in[3], d_in[6], d_in[7], d_in[12], d_in[13], d_in[10], d_in[11], d_in[14], d_in[15], d_in[17],
        wv, flags);
    norm_wt_kernel<<<(BTOT + 255) / 256, 256, 0, stream>>>(
        d_in[2], d_in[4], d_in[5], d_in[8], d_in[9], d_in[16], wbf, flags);

    const int EB = (ETOT + CHUNK - 1) / CHUNK;  // 416
    bucket_hist_kernel<<<EB, 256, 0, stream>>>(ei, flags, gbucket);
    bucket_scan_kernel<<<1, 256, 0, stream>>>(gbucket, bbase, bcursor);
    bin_pass_kernel<<<EB, 256, 0, stream>>>(ei, flags, bcursor, pairs);
    sort_pass_kernel<<<NB, 256, 0, stream>>>(pairs, bbase, srcs, offs);

    // degree-sorted perm (descending => LPT scheduling)
    deg_hist_kernel<<<NB, 256, 0, stream>>>(offs, gdeg);
    deg_scan_kernel<<<1, 256, 0, stream>>>(gdeg, dcursor);
    deg_scatter_kernel<<<NB, 256, 0, stream>>>(offs, dcursor, perm);

    const int GB = (NN + 127) / 128;  // 782
    const int AB = NN / 16;           // 6250 blocks, 4 dst/wave x 4 waves

    // proj: h0b = bf16(x @ Wp + bp)   (K=40 padded to 64)
    mfma_gemm<<<dim3(GB, 1), 256, 0, stream>>>(xb, MM, wbf + BWp, 64, wv + Vbp,
                                               NN, 2, HID, nullptr, h0b, nullptr, HID, 2, flags);

    // layer 1: hl/hr in one dispatch
    mfma_gemm<<<dim3(GB, 2), 256, 0, stream>>>(h0b, HID, wbf + BW1l, HID, nullptr,
                                               NN, 4, HID, nullptr, hlb, hrb, HID, 2, flags);
    gat_agg_kernel<<<AB, 256, 0, stream>>>(hlb, hrb, h0b, wv + Vatt1, wv + Vb1,
                                           wv + Vg1, wv + Vbe1, offs, srcs, perm, h1b);

    // layer 2
    mfma_gemm<<<dim3(GB, 2), 256, 0, stream>>>(h1b, HID, wbf + BW2l, HID, nullptr,
                                               NN, 4, HID, nullptr, hlb, hrb, HID, 2, flags);
    gat_agg_kernel<<<AB, 256, 0, stream>>>(hlb, hrb, h1b, wv + Vatt2, wv + Vb2,
                                           wv + Vg2, wv + Vbe2, offs, srcs, perm, h0b);

    // final: out = h @ Wo + bo (dtype per flags)
    mfma_gemm<<<dim3(GB, 1), 256, 0, stream>>>(h0b, HID, wbf + BWo, HID, wv + Vbo,
                                               NN, 4, LAT, (float*)d_out, (u16*)d_out, nullptr, LAT, -1, flags);
}